// Round 12
// baseline (120.783 us; speedup 1.0000x reference)
//
#include <hip/hip_runtime.h>
#include <math.h>

#define BB 2
#define LL 5
#define NN 10
#define CC 64
#define HH 128
#define WW 256
#define PP (HH*WW)          // 32768
#define NP (NN*PP)          // 327680

// ---------------- ws float layout ----------------
// [64..319]   avg_part (256)
// [320..575]  mx_part  (256)
// [576..1855] cntp (1280 per-block mask-count partials)
// [4096 .. 4096+NP)  mask

// fused conf+gaussian+threshold stencil: one block per (agent n, row h).
__global__ __launch_bounds__(256) void k_confmask(const float* __restrict__ psm,
                                                  const float* __restrict__ inv_delay,
                                                  const float* __restrict__ ewc_w,
                                                  const float* __restrict__ ewc_b,
                                                  float* __restrict__ mask,
                                                  float* __restrict__ cntp) {
    const float g0 = 0.15915494309189535f;
    const float g1 = 0.09653235263005391f;
    const float g2 = 0.05854983152431917f;
    const float g4 = 0.02153927930184936f;
    const float g5 = 0.01306423328468446f;
    const float g8 = 0.00291502449738744f;
    const float G[25] = { g8,g5,g4,g5,g8,
                          g5,g2,g1,g2,g5,
                          g4,g1,g0,g1,g4,
                          g5,g2,g1,g2,g5,
                          g8,g5,g4,g5,g8 };
    int blk = blockIdx.x;           // 0..1279
    int n   = blk >> 7;             // agent
    int h   = blk & 127;            // row
    int t   = threadIdx.x;          // col
    float enc = tanhf(inv_delay[n] * ewc_w[0] + ewc_b[0]) + 1.0f;
    const float* pn0 = psm + (n * 2 + 0) * PP;
    const float* pn1 = psm + (n * 2 + 1) * PP;

    __shared__ float cs[5][WW];
#pragma unroll
    for (int r = 0; r < 5; ++r) {
        int row = h - 2 + r;
        float v = 0.0f;
        if ((unsigned)row < (unsigned)HH) {
            float a0 = pn0[row * WW + t];
            float a1 = pn1[row * WW + t];
            v = fmaxf(1.0f / (1.0f + expf(-a0)), 1.0f / (1.0f + expf(-a1))) * enc;
        }
        cs[r][t] = v;
    }
    __syncthreads();

    float acc = 0.0f;
#pragma unroll
    for (int r = 0; r < 5; ++r) {
#pragma unroll
        for (int dx = -2; dx <= 2; ++dx) {
            int col = t + dx;
            if ((unsigned)col < (unsigned)WW)
                acc += cs[r][col] * G[r * 5 + (dx + 2)];
        }
    }
    float mv = (acc > 0.01f) ? 1.0f : 0.0f;
    if ((n % LL) == 0) mv = 1.0f;             // ego always communicates
    mask[n * PP + h * WW + t] = mv;

    float v = mv;
#pragma unroll
    for (int o = 32; o > 0; o >>= 1) v += __shfl_down(v, o, 64);
    __shared__ float sred[4];
    int lane = t & 63, wid = t >> 6;
    if (lane == 0) sred[wid] = v;
    __syncthreads();
    if (t == 0) cntp[blk] = sred[0] + sred[1] + sred[2] + sred[3];
}

// scores + softmax + fuse, x read once as float2 (8B/lane, G13 sweet spot).
// 16 waves x 4 channels per 128-pixel block; xr = 40 floats/thread -> VGPR
// ~90 (16-wave block resident under the 128-VGPR bound). Single variable vs
// R9: load width 4B->8B. No folds (R10/R11), no min-waves (R6), no atomics.
__global__ __launch_bounds__(1024) void k_attnfuse(const float* __restrict__ x,
                                                   const float* __restrict__ mask,
                                                   const float* __restrict__ inv_delay,
                                                   const float* __restrict__ ew_w,
                                                   const float* __restrict__ ew_b,
                                                   float* __restrict__ out) {
    int blk = blockIdx.x;           // 0..511
    int b   = blk >> 8;             // 256 tiles per batch
    int tid = threadIdx.x;
    int lane = tid & 63;
    int wv   = tid >> 6;            // 0..15
    int p0 = ((blk & 255) << 7) + (lane << 1);   // 128 pixels per block
    const float* xb = x + b * (LL * CC * PP) + p0;
    int cbase = wv << 2;            // 4 channels per wave

    float2 xr[4][5];
    float2 s5[5];
#pragma unroll
    for (int l = 0; l < LL; ++l) { s5[l].x = 0.f; s5[l].y = 0.f; }
#pragma unroll
    for (int cc = 0; cc < 4; ++cc) {
        const float* xc = xb + (cbase + cc) * PP;
#pragma unroll
        for (int l = 0; l < LL; ++l)
            xr[cc][l] = *(const float2*)(xc + l * CC * PP);
        float2 q = xr[cc][0];
#pragma unroll
        for (int l = 0; l < LL; ++l) {
            s5[l].x += q.x * xr[cc][l].x;
            s5[l].y += q.y * xr[cc][l].y;
        }
    }
    __shared__ float2 sred[16][5][64];   // 40 KB
#pragma unroll
    for (int l = 0; l < LL; ++l) sred[wv][l][lane] = s5[l];
    __syncthreads();

    // all waves redundantly finish the softmax (no second sync needed)
    float ew0 = ew_w[0], eb0 = ew_b[0];
    float2 a[5];
    {
        float2 m[5], sc[5], e[5];
#pragma unroll
        for (int l = 0; l < LL; ++l) {
            float2 tl; tl.x = 0.f; tl.y = 0.f;
#pragma unroll
            for (int w = 0; w < 16; ++w) {
                float2 v = sred[w][l][lane];
                tl.x += v.x; tl.y += v.y;
            }
            float en = tanhf(inv_delay[b * LL + l] * ew0 + eb0) + 1.0f;
            float2 mk = *(const float2*)(mask + (b * LL + l) * PP + p0);
            m[l].x = en * mk.x;
            m[l].y = en * mk.y;
            sc[l] = tl;                  // raw scores; scale applied below
        }
        const float scale = 0.125f;      // 1/sqrt(64)
#pragma unroll
        for (int l = 0; l < LL; ++l) {
            sc[l].x = sc[l].x * m[0].x * m[l].x * scale;
            sc[l].y = sc[l].y * m[0].y * m[l].y * scale;
        }
        float2 mx;
        mx.x = fmaxf(fmaxf(fmaxf(sc[0].x, sc[1].x), fmaxf(sc[2].x, sc[3].x)), sc[4].x);
        mx.y = fmaxf(fmaxf(fmaxf(sc[0].y, sc[1].y), fmaxf(sc[2].y, sc[3].y)), sc[4].y);
        float2 sum; sum.x = 0.f; sum.y = 0.f;
#pragma unroll
        for (int l = 0; l < LL; ++l) {
            e[l].x = expf(sc[l].x - mx.x);
            e[l].y = expf(sc[l].y - mx.y);
            sum.x += e[l].x; sum.y += e[l].y;
        }
        float2 inv; inv.x = 1.0f / sum.x; inv.y = 1.0f / sum.y;
#pragma unroll
        for (int l = 0; l < LL; ++l) {
            a[l].x = e[l].x * inv.x * m[l].x;
            a[l].y = e[l].y * inv.y * m[l].y;
        }
    }

    float* ob = out + b * (CC * PP) + p0;
#pragma unroll
    for (int cc = 0; cc < 4; ++cc) {
        float2 f; f.x = 0.f; f.y = 0.f;
#pragma unroll
        for (int l = 0; l < LL; ++l) {
            f.x += a[l].x * xr[cc][l].x;
            f.y += a[l].y * xr[cc][l].y;
        }
        *(float2*)(ob + (cbase + cc) * PP) = f;
    }
}

// 256 blocks: block = half of one (b,c) row -> partials (out is L2/L3-warm)
__global__ void k_reduce(const float* __restrict__ xfuse,
                         float* __restrict__ avg_part,
                         float* __restrict__ mx_part) {
    int blk = blockIdx.x;               // 256
    int bc = blk >> 1;
    int half = blk & 1;
    const float4* row = (const float4*)(xfuse + bc * PP) + half * 4096;
    float s = 0.0f, m = -INFINITY;
    for (int i = threadIdx.x; i < 4096; i += 256) {
        float4 v = row[i];
        s += v.x + v.y + v.z + v.w;
        m = fmaxf(m, fmaxf(fmaxf(v.x, v.y), fmaxf(v.z, v.w)));
    }
#pragma unroll
    for (int o = 32; o > 0; o >>= 1) {
        s += __shfl_down(s, o, 64);
        m = fmaxf(m, __shfl_down(m, o, 64));
    }
    __shared__ float ss[4], sm[4];
    int lane = threadIdx.x & 63, wid = threadIdx.x >> 6;
    if (lane == 0) { ss[wid] = s; sm[wid] = m; }
    __syncthreads();
    if (threadIdx.x == 0) {
        avg_part[blk] = ss[0] + ss[1] + ss[2] + ss[3];
        mx_part[blk]  = fmaxf(fmaxf(sm[0], sm[1]), fmaxf(sm[2], sm[3]));
    }
}

// gate (recomputed per block from partials) + scale; block 0 also sums cntp.
__global__ __launch_bounds__(256) void k_scalegate(float* __restrict__ out,
                                                   const float* __restrict__ avg_part,
                                                   const float* __restrict__ mx_part,
                                                   const float* __restrict__ w1,
                                                   const float* __restrict__ w2,
                                                   const float* __restrict__ cntp) {
    int idx = blockIdx.x * 256 + threadIdx.x;   // < B*C*PP/4; block spans ONE (b,c)
    int bc = idx >> 13;                         // PP/4 = 8192
    int b  = bc >> 6;
    int c  = bc & 63;
    __shared__ float hs[4];
    if (threadIdx.x < 4) {
        int j = threadIdx.x;
        float ha = 0.f, hm = 0.f;
        const float invP = 1.0f / (float)PP;
        for (int ch = 0; ch < CC; ++ch) {
            int i = (b * CC + ch) * 2;
            float av = (avg_part[i] + avg_part[i + 1]) * invP;
            float mv = fmaxf(mx_part[i], mx_part[i + 1]);
            float wv = w1[j * CC + ch];
            ha += av * wv;
            hm += mv * wv;
        }
        hs[j] = fmaxf(ha, 0.0f) + fmaxf(hm, 0.0f);
    }
    float4 v = ((float4*)out)[idx];
    __syncthreads();
    float g = hs[0] * w2[c * 4 + 0] + hs[1] * w2[c * 4 + 1]
            + hs[2] * w2[c * 4 + 2] + hs[3] * w2[c * 4 + 3];
    float gate = 1.0f / (1.0f + expf(-g));
    v.x *= gate; v.y *= gate; v.z *= gate; v.w *= gate;
    ((float4*)out)[idx] = v;

    if (blockIdx.x == 0) {
        float s = 0.0f;
        for (int j = threadIdx.x; j < 1280; j += 256) s += cntp[j];
#pragma unroll
        for (int o = 32; o > 0; o >>= 1) s += __shfl_down(s, o, 64);
        __shared__ float cs2[4];
        int lane = threadIdx.x & 63, wid = threadIdx.x >> 6;
        if (lane == 0) cs2[wid] = s;
        __syncthreads();
        if (threadIdx.x == 0)
            out[BB * CC * PP] = (cs2[0] + cs2[1] + cs2[2] + cs2[3]) * (1.0f / (float)NP);
    }
}

extern "C" void kernel_launch(void* const* d_in, const int* in_sizes, int n_in,
                              void* d_out, int out_size, void* d_ws, size_t ws_size,
                              hipStream_t stream) {
    const float* x         = (const float*)d_in[0];
    const float* psm       = (const float*)d_in[1];
    const float* inv_delay = (const float*)d_in[2];
    const float* ew_w      = (const float*)d_in[3];
    const float* ew_b      = (const float*)d_in[4];
    const float* ewc_w     = (const float*)d_in[5];
    const float* ewc_b     = (const float*)d_in[6];
    const float* w1        = (const float*)d_in[7];
    const float* w2        = (const float*)d_in[8];
    float* out = (float*)d_out;
    float* wsf = (float*)d_ws;

    float* avgp = wsf + 64;
    float* mxp  = wsf + 320;
    float* cntp = wsf + 576;
    float* mask = wsf + 4096;

    k_confmask<<<NN * HH, 256, 0, stream>>>(psm, inv_delay, ewc_w, ewc_b, mask, cntp);
    k_attnfuse<<<512, 1024, 0, stream>>>(x, mask, inv_delay, ew_w, ew_b, out);
    k_reduce<<<256, 256, 0, stream>>>(out, avgp, mxp);
    k_scalegate<<<BB * CC * PP / 4 / 256, 256, 0, stream>>>(out, avgp, mxp, w1, w2, cntp);
}

// Round 13
// 76.485 us; speedup vs baseline: 1.5792x; 1.5792x over previous
//
#include <hip/hip_runtime.h>
#include <math.h>

#define BB 2
#define LL 5
#define NN 10
#define CC 64
#define HH 128
#define WW 256
#define PP (HH*WW)          // 32768
#define NP (NN*PP)          // 327680

// ---------------- ws float layout ----------------
// [64..319]   avg_part (256)
// [320..575]  mx_part  (256)
// [576..1855] cntp (1280 per-block mask-count partials)
// [4096 .. 4096+NP)  mask

// fused conf+gaussian+threshold stencil: one block per (agent n, row h).
__global__ __launch_bounds__(256) void k_confmask(const float* __restrict__ psm,
                                                  const float* __restrict__ inv_delay,
                                                  const float* __restrict__ ewc_w,
                                                  const float* __restrict__ ewc_b,
                                                  float* __restrict__ mask,
                                                  float* __restrict__ cntp) {
    const float g0 = 0.15915494309189535f;
    const float g1 = 0.09653235263005391f;
    const float g2 = 0.05854983152431917f;
    const float g4 = 0.02153927930184936f;
    const float g5 = 0.01306423328468446f;
    const float g8 = 0.00291502449738744f;
    const float G[25] = { g8,g5,g4,g5,g8,
                          g5,g2,g1,g2,g5,
                          g4,g1,g0,g1,g4,
                          g5,g2,g1,g2,g5,
                          g8,g5,g4,g5,g8 };
    int blk = blockIdx.x;           // 0..1279
    int n   = blk >> 7;             // agent
    int h   = blk & 127;            // row
    int t   = threadIdx.x;          // col
    float enc = tanhf(inv_delay[n] * ewc_w[0] + ewc_b[0]) + 1.0f;
    const float* pn0 = psm + (n * 2 + 0) * PP;
    const float* pn1 = psm + (n * 2 + 1) * PP;

    __shared__ float cs[5][WW];
#pragma unroll
    for (int r = 0; r < 5; ++r) {
        int row = h - 2 + r;
        float v = 0.0f;
        if ((unsigned)row < (unsigned)HH) {
            float a0 = pn0[row * WW + t];
            float a1 = pn1[row * WW + t];
            v = fmaxf(1.0f / (1.0f + expf(-a0)), 1.0f / (1.0f + expf(-a1))) * enc;
        }
        cs[r][t] = v;
    }
    __syncthreads();

    float acc = 0.0f;
#pragma unroll
    for (int r = 0; r < 5; ++r) {
#pragma unroll
        for (int dx = -2; dx <= 2; ++dx) {
            int col = t + dx;
            if ((unsigned)col < (unsigned)WW)
                acc += cs[r][col] * G[r * 5 + (dx + 2)];
        }
    }
    float mv = (acc > 0.01f) ? 1.0f : 0.0f;
    if ((n % LL) == 0) mv = 1.0f;             // ego always communicates
    mask[n * PP + h * WW + t] = mv;

    float v = mv;
#pragma unroll
    for (int o = 32; o > 0; o >>= 1) v += __shfl_down(v, o, 64);
    __shared__ float sred[4];
    int lane = t & 63, wid = t >> 6;
    if (lane == 0) sred[wid] = v;
    __syncthreads();
    if (t == 0) cntp[blk] = sred[0] + sred[1] + sred[2] + sred[3];
}

// scores + softmax + fuse, x read once as float2 (8B/lane).
// 512 thr = 8 waves x 8 channels, 128 pixels/block; xr = 80 floats/thread
// (R3-proven size). __launch_bounds__(512,4) pins the VGPR corridor at
// <=128: blocks the allocator's under-allocation spill (R5: 72, R12: 64)
// AND the over-allocation occupancy drop (R6: cap 256).
__global__ __launch_bounds__(512, 4) void k_attnfuse(const float* __restrict__ x,
                                                     const float* __restrict__ mask,
                                                     const float* __restrict__ inv_delay,
                                                     const float* __restrict__ ew_w,
                                                     const float* __restrict__ ew_b,
                                                     float* __restrict__ out) {
    int blk = blockIdx.x;           // 0..511
    int b   = blk >> 8;             // 256 tiles per batch
    int tid = threadIdx.x;
    int lane = tid & 63;
    int wv   = tid >> 6;            // 0..7
    int p0 = ((blk & 255) << 7) + (lane << 1);   // 128 pixels per block
    const float* xb = x + b * (LL * CC * PP) + p0;
    int cbase = wv << 3;            // 8 channels per wave

    float2 xr[8][5];
    float2 s5[5];
#pragma unroll
    for (int l = 0; l < LL; ++l) { s5[l].x = 0.f; s5[l].y = 0.f; }
#pragma unroll
    for (int cc = 0; cc < 8; ++cc) {
        const float* xc = xb + (cbase + cc) * PP;
#pragma unroll
        for (int l = 0; l < LL; ++l)
            xr[cc][l] = *(const float2*)(xc + l * CC * PP);
        float2 q = xr[cc][0];
#pragma unroll
        for (int l = 0; l < LL; ++l) {
            s5[l].x += q.x * xr[cc][l].x;
            s5[l].y += q.y * xr[cc][l].y;
        }
    }
    __shared__ float2 sred[8][5][64];    // 20 KB
#pragma unroll
    for (int l = 0; l < LL; ++l) sred[wv][l][lane] = s5[l];
    __syncthreads();

    // all waves redundantly finish the softmax (no second sync needed)
    float ew0 = ew_w[0], eb0 = ew_b[0];
    float2 a[5];
    {
        float2 m[5], sc[5], e[5];
#pragma unroll
        for (int l = 0; l < LL; ++l) {
            float2 tl; tl.x = 0.f; tl.y = 0.f;
#pragma unroll
            for (int w = 0; w < 8; ++w) {
                float2 v = sred[w][l][lane];
                tl.x += v.x; tl.y += v.y;
            }
            float en = tanhf(inv_delay[b * LL + l] * ew0 + eb0) + 1.0f;
            float2 mk = *(const float2*)(mask + (b * LL + l) * PP + p0);
            m[l].x = en * mk.x;
            m[l].y = en * mk.y;
            sc[l] = tl;
        }
        const float scale = 0.125f;      // 1/sqrt(64)
#pragma unroll
        for (int l = 0; l < LL; ++l) {
            sc[l].x = sc[l].x * m[0].x * m[l].x * scale;
            sc[l].y = sc[l].y * m[0].y * m[l].y * scale;
        }
        float2 mx;
        mx.x = fmaxf(fmaxf(fmaxf(sc[0].x, sc[1].x), fmaxf(sc[2].x, sc[3].x)), sc[4].x);
        mx.y = fmaxf(fmaxf(fmaxf(sc[0].y, sc[1].y), fmaxf(sc[2].y, sc[3].y)), sc[4].y);
        float2 sum; sum.x = 0.f; sum.y = 0.f;
#pragma unroll
        for (int l = 0; l < LL; ++l) {
            e[l].x = expf(sc[l].x - mx.x);
            e[l].y = expf(sc[l].y - mx.y);
            sum.x += e[l].x; sum.y += e[l].y;
        }
        float2 inv; inv.x = 1.0f / sum.x; inv.y = 1.0f / sum.y;
#pragma unroll
        for (int l = 0; l < LL; ++l) {
            a[l].x = e[l].x * inv.x * m[l].x;
            a[l].y = e[l].y * inv.y * m[l].y;
        }
    }

    float* ob = out + b * (CC * PP) + p0;
#pragma unroll
    for (int cc = 0; cc < 8; ++cc) {
        float2 f; f.x = 0.f; f.y = 0.f;
#pragma unroll
        for (int l = 0; l < LL; ++l) {
            f.x += a[l].x * xr[cc][l].x;
            f.y += a[l].y * xr[cc][l].y;
        }
        *(float2*)(ob + (cbase + cc) * PP) = f;
    }
}

// 256 blocks: block = half of one (b,c) row -> partials (out is L2/L3-warm)
__global__ void k_reduce(const float* __restrict__ xfuse,
                         float* __restrict__ avg_part,
                         float* __restrict__ mx_part) {
    int blk = blockIdx.x;               // 256
    int bc = blk >> 1;
    int half = blk & 1;
    const float4* row = (const float4*)(xfuse + bc * PP) + half * 4096;
    float s = 0.0f, m = -INFINITY;
    for (int i = threadIdx.x; i < 4096; i += 256) {
        float4 v = row[i];
        s += v.x + v.y + v.z + v.w;
        m = fmaxf(m, fmaxf(fmaxf(v.x, v.y), fmaxf(v.z, v.w)));
    }
#pragma unroll
    for (int o = 32; o > 0; o >>= 1) {
        s += __shfl_down(s, o, 64);
        m = fmaxf(m, __shfl_down(m, o, 64));
    }
    __shared__ float ss[4], sm[4];
    int lane = threadIdx.x & 63, wid = threadIdx.x >> 6;
    if (lane == 0) { ss[wid] = s; sm[wid] = m; }
    __syncthreads();
    if (threadIdx.x == 0) {
        avg_part[blk] = ss[0] + ss[1] + ss[2] + ss[3];
        mx_part[blk]  = fmaxf(fmaxf(sm[0], sm[1]), fmaxf(sm[2], sm[3]));
    }
}

// gate (recomputed per block from partials) + scale; block 0 also sums cntp.
__global__ __launch_bounds__(256) void k_scalegate(float* __restrict__ out,
                                                   const float* __restrict__ avg_part,
                                                   const float* __restrict__ mx_part,
                                                   const float* __restrict__ w1,
                                                   const float* __restrict__ w2,
                                                   const float* __restrict__ cntp) {
    int idx = blockIdx.x * 256 + threadIdx.x;   // < B*C*PP/4; block spans ONE (b,c)
    int bc = idx >> 13;                         // PP/4 = 8192
    int b  = bc >> 6;
    int c  = bc & 63;
    __shared__ float hs[4];
    if (threadIdx.x < 4) {
        int j = threadIdx.x;
        float ha = 0.f, hm = 0.f;
        const float invP = 1.0f / (float)PP;
        for (int ch = 0; ch < CC; ++ch) {
            int i = (b * CC + ch) * 2;
            float av = (avg_part[i] + avg_part[i + 1]) * invP;
            float mv = fmaxf(mx_part[i], mx_part[i + 1]);
            float wv = w1[j * CC + ch];
            ha += av * wv;
            hm += mv * wv;
        }
        hs[j] = fmaxf(ha, 0.0f) + fmaxf(hm, 0.0f);
    }
    float4 v = ((float4*)out)[idx];
    __syncthreads();
    float g = hs[0] * w2[c * 4 + 0] + hs[1] * w2[c * 4 + 1]
            + hs[2] * w2[c * 4 + 2] + hs[3] * w2[c * 4 + 3];
    float gate = 1.0f / (1.0f + expf(-g));
    v.x *= gate; v.y *= gate; v.z *= gate; v.w *= gate;
    ((float4*)out)[idx] = v;

    if (blockIdx.x == 0) {
        float s = 0.0f;
        for (int j = threadIdx.x; j < 1280; j += 256) s += cntp[j];
#pragma unroll
        for (int o = 32; o > 0; o >>= 1) s += __shfl_down(s, o, 64);
        __shared__ float cs2[4];
        int lane = threadIdx.x & 63, wid = threadIdx.x >> 6;
        if (lane == 0) cs2[wid] = s;
        __syncthreads();
        if (threadIdx.x == 0)
            out[BB * CC * PP] = (cs2[0] + cs2[1] + cs2[2] + cs2[3]) * (1.0f / (float)NP);
    }
}

extern "C" void kernel_launch(void* const* d_in, const int* in_sizes, int n_in,
                              void* d_out, int out_size, void* d_ws, size_t ws_size,
                              hipStream_t stream) {
    const float* x         = (const float*)d_in[0];
    const float* psm       = (const float*)d_in[1];
    const float* inv_delay = (const float*)d_in[2];
    const float* ew_w      = (const float*)d_in[3];
    const float* ew_b      = (const float*)d_in[4];
    const float* ewc_w     = (const float*)d_in[5];
    const float* ewc_b     = (const float*)d_in[6];
    const float* w1        = (const float*)d_in[7];
    const float* w2        = (const float*)d_in[8];
    float* out = (float*)d_out;
    float* wsf = (float*)d_ws;

    float* avgp = wsf + 64;
    float* mxp  = wsf + 320;
    float* cntp = wsf + 576;
    float* mask = wsf + 4096;

    k_confmask<<<NN * HH, 256, 0, stream>>>(psm, inv_delay, ewc_w, ewc_b, mask, cntp);
    k_attnfuse<<<512, 512, 0, stream>>>(x, mask, inv_delay, ew_w, ew_b, out);
    k_reduce<<<256, 256, 0, stream>>>(out, avgp, mxp);
    k_scalegate<<<BB * CC * PP / 4 / 256, 256, 0, stream>>>(out, avgp, mxp, w1, w2, cntp);
}

// Round 14
// 54.147 us; speedup vs baseline: 2.2306x; 1.4125x over previous
//
#include <hip/hip_runtime.h>
#include <math.h>

#define BB 2
#define LL 5
#define NN 10
#define CC 64
#define HH 128
#define WW 256
#define PP (HH*WW)          // 32768
#define NP (NN*PP)          // 327680

// ---------------- ws float layout ----------------
// [64..319]   avg_part (256)
// [320..575]  mx_part  (256)
// [576..1855] cntp (1280 per-block mask-count partials)
// [4096 .. 4096+NP)  mask

// fused conf+gaussian+threshold stencil: one block per (agent n, row h).
__global__ __launch_bounds__(256) void k_confmask(const float* __restrict__ psm,
                                                  const float* __restrict__ inv_delay,
                                                  const float* __restrict__ ewc_w,
                                                  const float* __restrict__ ewc_b,
                                                  float* __restrict__ mask,
                                                  float* __restrict__ cntp) {
    const float g0 = 0.15915494309189535f;
    const float g1 = 0.09653235263005391f;
    const float g2 = 0.05854983152431917f;
    const float g4 = 0.02153927930184936f;
    const float g5 = 0.01306423328468446f;
    const float g8 = 0.00291502449738744f;
    const float G[25] = { g8,g5,g4,g5,g8,
                          g5,g2,g1,g2,g5,
                          g4,g1,g0,g1,g4,
                          g5,g2,g1,g2,g5,
                          g8,g5,g4,g5,g8 };
    int blk = blockIdx.x;           // 0..1279
    int n   = blk >> 7;             // agent
    int h   = blk & 127;            // row
    int t   = threadIdx.x;          // col
    float enc = tanhf(inv_delay[n] * ewc_w[0] + ewc_b[0]) + 1.0f;
    const float* pn0 = psm + (n * 2 + 0) * PP;
    const float* pn1 = psm + (n * 2 + 1) * PP;

    __shared__ float cs[5][WW];
#pragma unroll
    for (int r = 0; r < 5; ++r) {
        int row = h - 2 + r;
        float v = 0.0f;
        if ((unsigned)row < (unsigned)HH) {
            float a0 = pn0[row * WW + t];
            float a1 = pn1[row * WW + t];
            v = fmaxf(1.0f / (1.0f + expf(-a0)), 1.0f / (1.0f + expf(-a1))) * enc;
        }
        cs[r][t] = v;
    }
    __syncthreads();

    float acc = 0.0f;
#pragma unroll
    for (int r = 0; r < 5; ++r) {
#pragma unroll
        for (int dx = -2; dx <= 2; ++dx) {
            int col = t + dx;
            if ((unsigned)col < (unsigned)WW)
                acc += cs[r][col] * G[r * 5 + (dx + 2)];
        }
    }
    float mv = (acc > 0.01f) ? 1.0f : 0.0f;
    if ((n % LL) == 0) mv = 1.0f;             // ego always communicates
    mask[n * PP + h * WW + t] = mv;

    float v = mv;
#pragma unroll
    for (int o = 32; o > 0; o >>= 1) v += __shfl_down(v, o, 64);
    __shared__ float sred[4];
    int lane = t & 63, wid = t >> 6;
    if (lane == 0) sred[wid] = v;
    __syncthreads();
    if (t == 0) cntp[blk] = sred[0] + sred[1] + sred[2] + sred[3];
}

// scores + softmax + fuse, x read once (scalar loads, R9-exact core).
// ONE change vs R9: XCD-aware pixel-block swizzle. Default dispatch round-
// robins consecutive blocks across the 8 XCDs, so each XCD's L2 sees 256B
// islands per plane. Remap pb=(pb&7)*64+(pb>>3) (bijective, 512=8*64) so
// blocks with blk%8==x cover a CONTIGUOUS 64-block pixel range -> each XCD
// streams 16KB contiguous spans per plane. No folds/atomics/min-waves
// (R5/R6/R8/R10-R13 all regressed).
__global__ __launch_bounds__(512) void k_attnfuse(const float* __restrict__ x,
                                                  const float* __restrict__ mask,
                                                  const float* __restrict__ inv_delay,
                                                  const float* __restrict__ ew_w,
                                                  const float* __restrict__ ew_b,
                                                  float* __restrict__ out) {
    int blk = blockIdx.x;
    int b   = blk >> 9;                 // 512 blocks per batch
    int lane = threadIdx.x & 63;
    int wv   = threadIdx.x >> 6;        // 0..7
    int pb = blk & 511;
    pb = ((pb & 7) << 6) | (pb >> 3);   // XCD-contiguous pixel-block remap
    int p = (pb << 6) + lane;
    const float* xb = x + b * (LL * CC * PP) + p;
    int cbase = wv << 3;                // 8 channels per wave

    float xr[8][5];
    float s5[5] = {0.f, 0.f, 0.f, 0.f, 0.f};
#pragma unroll
    for (int cc = 0; cc < 8; ++cc) {
        const float* xc = xb + (cbase + cc) * PP;
#pragma unroll
        for (int l = 0; l < LL; ++l) xr[cc][l] = xc[l * CC * PP];
        float q = xr[cc][0];
#pragma unroll
        for (int l = 0; l < LL; ++l) s5[l] += q * xr[cc][l];
    }

    __shared__ float sred[8][5][64];
#pragma unroll
    for (int l = 0; l < LL; ++l) sred[wv][l][lane] = s5[l];
    __syncthreads();

    // all waves redundantly finish the softmax (no second sync needed)
    float ew0 = ew_w[0], eb0 = ew_b[0];
    float a[5];
    {
        float m[5], t[5], sc[5], e[5];
#pragma unroll
        for (int l = 0; l < LL; ++l) {
            float tl = 0.f;
#pragma unroll
            for (int w = 0; w < 8; ++w) tl += sred[w][l][lane];
            t[l] = tl;
            float en = tanhf(inv_delay[b * LL + l] * ew0 + eb0) + 1.0f;
            m[l] = en * mask[(b * LL + l) * PP + p];
        }
        const float scale = 0.125f;               // 1/sqrt(64)
#pragma unroll
        for (int l = 0; l < LL; ++l) sc[l] = t[l] * m[0] * m[l] * scale;
        float mxv = fmaxf(fmaxf(fmaxf(sc[0], sc[1]), fmaxf(sc[2], sc[3])), sc[4]);
        float sum = 0.f;
#pragma unroll
        for (int l = 0; l < LL; ++l) { e[l] = expf(sc[l] - mxv); sum += e[l]; }
        float inv = 1.0f / sum;
#pragma unroll
        for (int l = 0; l < LL; ++l) a[l] = e[l] * inv * m[l];
    }

    float* ob = out + b * (CC * PP) + p;
#pragma unroll
    for (int cc = 0; cc < 8; ++cc) {
        float f = 0.f;
#pragma unroll
        for (int l = 0; l < LL; ++l) f += a[l] * xr[cc][l];
        ob[(cbase + cc) * PP] = f;
    }
}

// 256 blocks: block = half of one (b,c) row -> partials (out is L2/L3-warm)
__global__ void k_reduce(const float* __restrict__ xfuse,
                         float* __restrict__ avg_part,
                         float* __restrict__ mx_part) {
    int blk = blockIdx.x;               // 256
    int bc = blk >> 1;
    int half = blk & 1;
    const float4* row = (const float4*)(xfuse + bc * PP) + half * 4096;
    float s = 0.0f, m = -INFINITY;
    for (int i = threadIdx.x; i < 4096; i += 256) {
        float4 v = row[i];
        s += v.x + v.y + v.z + v.w;
        m = fmaxf(m, fmaxf(fmaxf(v.x, v.y), fmaxf(v.z, v.w)));
    }
#pragma unroll
    for (int o = 32; o > 0; o >>= 1) {
        s += __shfl_down(s, o, 64);
        m = fmaxf(m, __shfl_down(m, o, 64));
    }
    __shared__ float ss[4], sm[4];
    int lane = threadIdx.x & 63, wid = threadIdx.x >> 6;
    if (lane == 0) { ss[wid] = s; sm[wid] = m; }
    __syncthreads();
    if (threadIdx.x == 0) {
        avg_part[blk] = ss[0] + ss[1] + ss[2] + ss[3];
        mx_part[blk]  = fmaxf(fmaxf(sm[0], sm[1]), fmaxf(sm[2], sm[3]));
    }
}

// gate (recomputed per block from partials) + scale; block 0 also sums cntp.
__global__ __launch_bounds__(256) void k_scalegate(float* __restrict__ out,
                                                   const float* __restrict__ avg_part,
                                                   const float* __restrict__ mx_part,
                                                   const float* __restrict__ w1,
                                                   const float* __restrict__ w2,
                                                   const float* __restrict__ cntp) {
    int idx = blockIdx.x * 256 + threadIdx.x;   // < B*C*PP/4; block spans ONE (b,c)
    int bc = idx >> 13;                         // PP/4 = 8192
    int b  = bc >> 6;
    int c  = bc & 63;
    __shared__ float hs[4];
    if (threadIdx.x < 4) {
        int j = threadIdx.x;
        float ha = 0.f, hm = 0.f;
        const float invP = 1.0f / (float)PP;
        for (int ch = 0; ch < CC; ++ch) {
            int i = (b * CC + ch) * 2;
            float av = (avg_part[i] + avg_part[i + 1]) * invP;
            float mv = fmaxf(mx_part[i], mx_part[i + 1]);
            float wv = w1[j * CC + ch];
            ha += av * wv;
            hm += mv * wv;
        }
        hs[j] = fmaxf(ha, 0.0f) + fmaxf(hm, 0.0f);
    }
    float4 v = ((float4*)out)[idx];
    __syncthreads();
    float g = hs[0] * w2[c * 4 + 0] + hs[1] * w2[c * 4 + 1]
            + hs[2] * w2[c * 4 + 2] + hs[3] * w2[c * 4 + 3];
    float gate = 1.0f / (1.0f + expf(-g));
    v.x *= gate; v.y *= gate; v.z *= gate; v.w *= gate;
    ((float4*)out)[idx] = v;

    if (blockIdx.x == 0) {
        float s = 0.0f;
        for (int j = threadIdx.x; j < 1280; j += 256) s += cntp[j];
#pragma unroll
        for (int o = 32; o > 0; o >>= 1) s += __shfl_down(s, o, 64);
        __shared__ float cs2[4];
        int lane = threadIdx.x & 63, wid = threadIdx.x >> 6;
        if (lane == 0) cs2[wid] = s;
        __syncthreads();
        if (threadIdx.x == 0)
            out[BB * CC * PP] = (cs2[0] + cs2[1] + cs2[2] + cs2[3]) * (1.0f / (float)NP);
    }
}

extern "C" void kernel_launch(void* const* d_in, const int* in_sizes, int n_in,
                              void* d_out, int out_size, void* d_ws, size_t ws_size,
                              hipStream_t stream) {
    const float* x         = (const float*)d_in[0];
    const float* psm       = (const float*)d_in[1];
    const float* inv_delay = (const float*)d_in[2];
    const float* ew_w      = (const float*)d_in[3];
    const float* ew_b      = (const float*)d_in[4];
    const float* ewc_w     = (const float*)d_in[5];
    const float* ewc_b     = (const float*)d_in[6];
    const float* w1        = (const float*)d_in[7];
    const float* w2        = (const float*)d_in[8];
    float* out = (float*)d_out;
    float* wsf = (float*)d_ws;

    float* avgp = wsf + 64;
    float* mxp  = wsf + 320;
    float* cntp = wsf + 576;
    float* mask = wsf + 4096;

    k_confmask<<<NN * HH, 256, 0, stream>>>(psm, inv_delay, ewc_w, ewc_b, mask, cntp);
    k_attnfuse<<<1024, 512, 0, stream>>>(x, mask, inv_delay, ew_w, ew_b, out);
    k_reduce<<<256, 256, 0, stream>>>(out, avgp, mxp);
    k_scalegate<<<BB * CC * PP / 4 / 256, 256, 0, stream>>>(out, avgp, mxp, w1, w2, cntp);
}